// Round 4
// baseline (484.833 us; speedup 1.0000x reference)
//
#include <hip/hip_runtime.h>
#include <hip/hip_bf16.h>
#include <string.h>

#define BB 128
#define UU 200
#define DD 512
#define NP 256
#define NWS 504   // blocks 0..503 write ws slices; 504..511 atomicAdd into out

typedef __attribute__((ext_vector_type(8))) short short8;
typedef __attribute__((ext_vector_type(4))) float f32x4;

__device__ __forceinline__ unsigned pack_bf16_2(float a, float b) {
    __hip_bfloat162 h = __float22bfloat162_rn(make_float2(a, b));
    unsigned u; memcpy(&u, &h, 4); return u;
}

__device__ __forceinline__ unsigned short f2bf(float x) {
    union { float f; unsigned u; } v; v.f = x;
    unsigned r = v.u + 0x7FFFu + ((v.u >> 16) & 1u);
    return (unsigned short)(r >> 16);
}

// ---- build swizzled bf16 kernel table.
// Element (n, j) -> Kb[(nb*64 + jb)*128 + nl*8 + jl], nb=n>>4, nl=n&15, jb=j>>3, jl=j&7.
// Value = bf16(kr)|bf16(ki)<<16; zero-padded for n>=200.
__global__ void kb_build_kernel(const float* __restrict__ Kt, unsigned* __restrict__ Kb) {
    int idx = blockIdx.x * 256 + threadIdx.x;    // 0..131071 (256 n x 512 j)
    int n = idx >> 9, j = idx & 511;
    unsigned v = 0u;
    if (n < UU) {
        float2 s = ((const float2*)Kt)[(size_t)n * DD + j];
        v = pack_bf16_2(s.x, s.y);
    }
    int nb = n >> 4, nl = n & 15, jb = j >> 3, jl = j & 7;
    Kb[((nb * 64 + jb) << 7) + (nl << 3) + jl] = v;
}

__global__ void zero_out_kernel(float* __restrict__ out) {
    int i = blockIdx.x * 256 + threadIdx.x;
    if (i < BB * UU) out[i] = 0.0f;
}

// ---- sum the 504 ws partials into out (out pre-zeroed; blocks 504..511 atomic'd in gemm)
__global__ void reduce_kernel(const float* __restrict__ ws, float* __restrict__ out) {
    int o = blockIdx.x * 256 + threadIdx.x;
    if (o >= BB * UU) return;
    int p0 = blockIdx.y * 36;                     // grid.y = 14, 14*36 = 504
    float s = 0.0f;
#pragma unroll
    for (int p = 0; p < 36; ++p)
        s += ws[(size_t)(p0 + p) * (BB * UU) + o];
    atomicAdd(&out[o], s);
}

// ---- main GEMM: block = one i-row; tile M=128 x N=256; waves 2m x 4n, wave tile 64x64.
// A staged fp32->bf16 in LDS (conflict-free pad+hash layout); B synthesized in registers.
__global__ __launch_bounds__(512, 4) void cm_gemm3_kernel(
    const float* __restrict__ Ar, const float* __restrict__ Ai,
    const float* __restrict__ Kt, const unsigned* __restrict__ Kb,
    float* __restrict__ ws, float* __restrict__ out)
{
    // 2 buffers x 128 rows x 80 shorts (64 data + 16 pad) = 40 KB total
    __shared__ short sA[2][128 * 80];

    const int tid  = threadIdx.x;
    const int irow = blockIdx.x;
    const int w    = tid >> 6;
    const int lane = tid & 63;
    const int wm   = w & 1;               // m-half (0,1)
    const int wn   = w >> 1;              // n-quarter (0..3)
    const int m0   = wm * 64;
    const int n0   = wn * 64;
    const int nb0  = n0 >> 4;             // n-block base for Kb addressing
    const int rrow = lane & 15;
    const int quad = lane >> 4;

    // per-n-slice kernel scalars (slice tj: n = n0 + tj*16 + rrow)
    float krI[4], kiI[4];
#pragma unroll
    for (int t = 0; t < 4; ++t) {
        int n = n0 + t * 16 + rrow;
        if (n < UU) {
            float2 kv = ((const float2*)Kt)[(size_t)n * DD + irow];
            krI[t] = kv.x; kiI[t] = kv.y;
        } else { krI[t] = 0.f; kiI[t] = 0.f; }
    }

    // ---- A staging assignment: thread -> (row = tid>>2, 16-float group p = tid&3)
    const int srow = tid >> 2;
    const int p    = tid & 3;
    const int hs   = (srow ^ (srow >> 3)) & 7;
    const size_t abase = (size_t)srow * (DD * DD) + (size_t)irow * DD + p * 16;
    const int wa0 = srow * 80 + (((2 * p)     ^ hs) * 8);
    const int wa1 = srow * 80 + (((2 * p + 1) ^ hs) * 8);

    // ---- A fragment read addresses (shorts): row m, granule (kk*4+quad)^h(m)
    int ra[4][2];
#pragma unroll
    for (int t = 0; t < 4; ++t) {
        int m  = m0 + t * 16 + rrow;
        int hm = (m ^ (m >> 3)) & 7;
        ra[t][0] = m * 80 + ((quad       ^ hm) * 8);
        ra[t][1] = m * 80 + (((4 + quad) ^ hm) * 8);
    }

    f32x4 acc[4][4];
#pragma unroll
    for (int a = 0; a < 4; ++a)
#pragma unroll
        for (int b = 0; b < 4; ++b) acc[a][b] = (f32x4)(0.f);

    // prefetch stage 0: Ar chunk 0
    f32x4 pf[4];
#pragma unroll
    for (int l = 0; l < 4; ++l) pf[l] = *(const f32x4*)(Ar + abase + l * 4);

    for (int c = 0; c < 8; ++c) {
#pragma unroll
        for (int ph = 0; ph < 2; ++ph) {
            short* sb = sA[ph];

            // convert prefetched fp32 -> bf16 LDS (hashed granules)
            uint4 g0, g1;
            g0.x = pack_bf16_2(pf[0][0], pf[0][1]);
            g0.y = pack_bf16_2(pf[0][2], pf[0][3]);
            g0.z = pack_bf16_2(pf[1][0], pf[1][1]);
            g0.w = pack_bf16_2(pf[1][2], pf[1][3]);
            g1.x = pack_bf16_2(pf[2][0], pf[2][1]);
            g1.y = pack_bf16_2(pf[2][2], pf[2][3]);
            g1.z = pack_bf16_2(pf[3][0], pf[3][1]);
            g1.w = pack_bf16_2(pf[3][2], pf[3][3]);
            *(uint4*)&sb[wa0] = g0;
            *(uint4*)&sb[wa1] = g1;
            __syncthreads();

            // issue next stage's global loads (fly during compute below)
            if (ph == 0) {
#pragma unroll
                for (int l = 0; l < 4; ++l)
                    pf[l] = *(const f32x4*)(Ai + abase + c * 64 + l * 4);
            } else if (c < 7) {
#pragma unroll
                for (int l = 0; l < 4; ++l)
                    pf[l] = *(const f32x4*)(Ar + abase + (c + 1) * 64 + l * 4);
            }

            // phase-uniform synthesis coefficients: w = P*kr + Q*ki
            float P[4], Q[4];
#pragma unroll
            for (int t = 0; t < 4; ++t) {
                P[t] = ph ? -kiI[t] : krI[t];
                Q[t] = ph ? -krI[t] : -kiI[t];
            }

            const unsigned kbase = (unsigned)(nb0 * 8192) + (unsigned)((c * 8 + quad) * 128) + (unsigned)(rrow * 8);
            uint4 nxa = *(const uint4*)(Kb + kbase);      // kk=0, tj=0
            uint4 nxb = *(const uint4*)(Kb + kbase + 4);

#pragma unroll
            for (int kk = 0; kk < 2; ++kk) {
                short8 af[4];
#pragma unroll
                for (int t = 0; t < 4; ++t)
                    af[t] = *(const short8*)&sb[ra[t][kk]];

#pragma unroll
                for (int tj = 0; tj < 4; ++tj) {
                    uint4 ca = nxa, cb = nxb;
                    if (!(kk == 1 && tj == 3)) {
                        int tn = (tj == 3) ? 0 : tj + 1;
                        int kn = (tj == 3) ? 1 : kk;
                        unsigned na = kbase + (unsigned)(tn * 8192) + (unsigned)(kn * 512);
                        nxa = *(const uint4*)(Kb + na);
                        nxb = *(const uint4*)(Kb + na + 4);
                    }
                    unsigned dw[8] = {ca.x, ca.y, ca.z, ca.w, cb.x, cb.y, cb.z, cb.w};
                    union { short8 v; unsigned u[4]; } bfr;
#pragma unroll
                    for (int e2 = 0; e2 < 4; ++e2) {
                        union { unsigned u; float f; } a0, b0, a1, b1;
                        a0.u = dw[2 * e2]     << 16;  b0.u = dw[2 * e2]     & 0xFFFF0000u;
                        a1.u = dw[2 * e2 + 1] << 16;  b1.u = dw[2 * e2 + 1] & 0xFFFF0000u;
                        float w0 = P[tj] * a0.f + Q[tj] * b0.f;
                        float w1 = P[tj] * a1.f + Q[tj] * b1.f;
                        bfr.u[e2] = pack_bf16_2(w0, w1);
                    }
#pragma unroll
                    for (int ti = 0; ti < 4; ++ti)
                        acc[ti][tj] = __builtin_amdgcn_mfma_f32_16x16x32_bf16(
                            af[ti], bfr.v, acc[ti][tj], 0, 0, 0);
                }
            }
        }
    }

    // ---- epilogue: split-K partials (plain stores; atomics only for last 8 blocks)
    if (irow < NWS) {
        float* wsp = ws + (size_t)irow * (BB * UU);
#pragma unroll
        for (int ti = 0; ti < 4; ++ti) {
            int m = m0 + ti * 16 + quad * 4;
#pragma unroll
            for (int tj = 0; tj < 4; ++tj) {
                int n = n0 + tj * 16 + rrow;
                if (n < UU) {
#pragma unroll
                    for (int r = 0; r < 4; ++r)
                        wsp[(size_t)(m + r) * UU + n] = acc[ti][tj][r];
                }
            }
        }
    } else {
#pragma unroll
        for (int ti = 0; ti < 4; ++ti) {
            int m = m0 + ti * 16 + quad * 4;
#pragma unroll
            for (int tj = 0; tj < 4; ++tj) {
                int n = n0 + tj * 16 + rrow;
                if (n < UU) {
#pragma unroll
                    for (int r = 0; r < 4; ++r)
                        atomicAdd(&out[(size_t)(m + r) * UU + n], acc[ti][tj][r]);
                }
            }
        }
    }
}

// ---- fallback (ws too small): proven atomic kernel (R2 structure)
#define ASTR 40
#define WSTR 40
__global__ __launch_bounds__(512, 4) void cm_gemm_fb_kernel(
    const float* __restrict__ Ar, const float* __restrict__ Ai,
    const float* __restrict__ Kt, float* __restrict__ dst)
{
    __shared__ short sAr[BB * ASTR];
    __shared__ short sAi[BB * ASTR];
    __shared__ short sWr[NP * WSTR];
    __shared__ short sWi[NP * WSTR];
    const int tid = threadIdx.x, irow = blockIdx.x;
    const int w = tid >> 6, lane = tid & 63;
    const int mw = (w & 1) * 64, nw = (w >> 1) * 64;
    const int rrow = lane & 15, quad = lane >> 4;
    const int nW = tid >> 1, jh = (tid & 1) * 16;
    float krI = 0.f, kiI = 0.f;
    if (nW < UU) { float2 s = ((const float2*)Kt)[(size_t)nW * DD + irow]; krI = s.x; kiI = s.y; }
    const int brow0 = tid >> 3, grp = tid & 7;
    const size_t aoff0 = (size_t)brow0 * DD * DD + (size_t)irow * DD + (size_t)grp * 4;
    const size_t aoff1 = aoff0 + (size_t)64 * DD * DD;
    f32x4 acc[4][4];
#pragma unroll
    for (int a = 0; a < 4; ++a)
#pragma unroll
        for (int b = 0; b < 4; ++b) acc[a][b] = (f32x4)(0.f);
    for (int jw = 0; jw < DD; jw += 32) {
        f32x4 vr0 = *(const f32x4*)(Ar + aoff0 + jw);
        f32x4 vr1 = *(const f32x4*)(Ar + aoff1 + jw);
        f32x4 vi0 = *(const f32x4*)(Ai + aoff0 + jw);
        f32x4 vi1 = *(const f32x4*)(Ai + aoff1 + jw);
        union { unsigned short s[4]; uint2 u; } t0, t1, t2, t3;
#pragma unroll
        for (int q = 0; q < 4; ++q) {
            t0.s[q] = f2bf(vr0[q]); t1.s[q] = f2bf(vr1[q]);
            t2.s[q] = f2bf(vi0[q]); t3.s[q] = f2bf(vi1[q]);
        }
        *(uint2*)&sAr[ brow0       * ASTR + grp * 4] = t0.u;
        *(uint2*)&sAr[(brow0 + 64) * ASTR + grp * 4] = t1.u;
        *(uint2*)&sAi[ brow0       * ASTR + grp * 4] = t2.u;
        *(uint2*)&sAi[(brow0 + 64) * ASTR + grp * 4] = t3.u;
        if (nW < UU) {
            const f32x4* kv = (const f32x4*)(Kt + (size_t)nW * DD * 2 + (size_t)(jw + jh) * 2);
#pragma unroll
            for (int q = 0; q < 8; ++q) {
                f32x4 v = kv[q];
                float wr0 = krI * v[0] - kiI * v[1], wi0 = -(krI * v[1] + kiI * v[0]);
                float wr1 = krI * v[2] - kiI * v[3], wi1 = -(krI * v[3] + kiI * v[2]);
                *(unsigned*)&sWr[nW * WSTR + jh + 2 * q] = (unsigned)f2bf(wr0) | ((unsigned)f2bf(wr1) << 16);
                *(unsigned*)&sWi[nW * WSTR + jh + 2 * q] = (unsigned)f2bf(wi0) | ((unsigned)f2bf(wi1) << 16);
            }
        } else {
#pragma unroll
            for (int q = 0; q < 8; ++q) {
                *(unsigned*)&sWr[nW * WSTR + jh + 2 * q] = 0u;
                *(unsigned*)&sWi[nW * WSTR + jh + 2 * q] = 0u;
            }
        }
        __syncthreads();
#pragma unroll
        for (int ph = 0; ph < 2; ++ph) {
            const short* sAp = ph ? sAi : sAr;
            const short* sWp = ph ? sWi : sWr;
            short8 af[4], bf[4];
#pragma unroll
            for (int t = 0; t < 4; ++t) {
                af[t] = *(const short8*)&sAp[(mw + t * 16 + rrow) * ASTR + quad * 8];
                bf[t] = *(const short8*)&sWp[(nw + t * 16 + rrow) * WSTR + quad * 8];
            }
#pragma unroll
            for (int ti = 0; ti < 4; ++ti)
#pragma unroll
                for (int tj = 0; tj < 4; ++tj)
                    acc[ti][tj] = __builtin_amdgcn_mfma_f32_16x16x32_bf16(af[ti], bf[tj], acc[ti][tj], 0, 0, 0);
        }
        __syncthreads();
    }
#pragma unroll
    for (int ti = 0; ti < 4; ++ti) {
        int m = mw + ti * 16 + quad * 4;
#pragma unroll
        for (int tj = 0; tj < 4; ++tj) {
            int n = nw + tj * 16 + rrow;
            if (n < UU)
#pragma unroll
                for (int r = 0; r < 4; ++r)
                    atomicAdd(&dst[(size_t)(m + r) * UU + n], acc[ti][tj][r]);
        }
    }
}

extern "C" void kernel_launch(void* const* d_in, const int* in_sizes, int n_in,
                              void* d_out, int out_size, void* d_ws, size_t ws_size,
                              hipStream_t stream) {
    const float* Ar = (const float*)d_in[0];
    const float* Ai = (const float*)d_in[1];
    const float* Kt = (const float*)d_in[2];
    float* out = (float*)d_out;

    const size_t kb_dwords = (size_t)NP * DD;                         // 131072
    const size_t ws_need = kb_dwords * 4 + (size_t)NWS * BB * UU * 4; // 52,133,888 B

    if (ws_size >= ws_need) {
        unsigned* Kb = (unsigned*)d_ws;
        float* ws = (float*)d_ws + kb_dwords;
        hipLaunchKernelGGL(kb_build_kernel, dim3(512), dim3(256), 0, stream, Kt, Kb);
        hipLaunchKernelGGL(zero_out_kernel, dim3(100), dim3(256), 0, stream, out);
        hipLaunchKernelGGL(cm_gemm3_kernel, dim3(DD), dim3(512), 0, stream,
                           Ar, Ai, Kt, Kb, ws, out);
        hipLaunchKernelGGL(reduce_kernel, dim3(100, 14), dim3(256), 0, stream, ws, out);
    } else {
        hipLaunchKernelGGL(zero_out_kernel, dim3(100), dim3(256), 0, stream, out);
        hipLaunchKernelGGL(cm_gemm_fb_kernel, dim3(DD), dim3(512), 0, stream, Ar, Ai, Kt, out);
    }
}